// Round 1
// baseline (93.379 us; speedup 1.0000x reference)
//
#include <hip/hip_runtime.h>

// TauLoss: 1 - mean_c [ sum_{i,j} sign(y[c,i]-y[c,j]) * tanh(p[c,i]-p[c,j]) / (N*(N-1)) ]
// Identities used:
//   tanh(d*s) = s*tanh(d) for s in {-1,0,1}
//   tanh(a-b) = (ta - tb) / (1 - ta*tb), ta=tanh(a)  -> tanh computed once per
//   element (131K evals) instead of once per pair (134M evals).
// Diagonal pairs contribute exactly 0 (num=0), so the j-loop runs unmasked.

#define TAU_N 1024
#define TAU_C 128
#define TAU_SPLIT 4                 // i-tiles per column
#define TAU_BLOCK 256               // == TAU_N / TAU_SPLIT, one i per thread
#define TAU_NBLOCKS (TAU_C * TAU_SPLIT)

__device__ __forceinline__ float tau_step(float ti, float li, float2 v, float acc) {
    float num = ti - v.x;
    float den = __builtin_fmaf(-ti, v.x, 1.0f);       // 1 - ti*tj  in (0,2]
    float val = num * __builtin_amdgcn_rcpf(den);     // tanh(p_i - p_j)
    float s = (li > v.y) ? 1.0f : ((li < v.y) ? -1.0f : 0.0f);
    return __builtin_fmaf(s, val, acc);
}

__global__ __launch_bounds__(TAU_BLOCK) void tau_pairs_kernel(
        const float* __restrict__ pred, const float* __restrict__ y,
        float* __restrict__ partials) {
    __shared__ float2 row[TAU_N];         // (tanh(p), y) for this column
    __shared__ float wsum[TAU_BLOCK / 64];

    const int c    = blockIdx.x / TAU_SPLIT;
    const int tile = blockIdx.x % TAU_SPLIT;
    const int tid  = threadIdx.x;

    const float* p = pred + c * TAU_N;
    const float* l = y    + c * TAU_N;

    // Stage column into LDS: (tanh(p), y). 4 elements per thread.
    for (int k = tid; k < TAU_N; k += TAU_BLOCK) {
        float2 v;
        v.x = tanhf(p[k]);
        v.y = l[k];
        row[k] = v;
    }
    __syncthreads();

    const int   i  = tile * TAU_BLOCK + tid;
    const float ti = row[i].x;
    const float li = row[i].y;

    // 4 independent accumulators to hide v_rcp latency.
    float a0 = 0.f, a1 = 0.f, a2 = 0.f, a3 = 0.f;
#pragma unroll 2
    for (int j = 0; j < TAU_N; j += 4) {
        float2 v0 = row[j + 0];
        float2 v1 = row[j + 1];
        float2 v2 = row[j + 2];
        float2 v3 = row[j + 3];
        a0 = tau_step(ti, li, v0, a0);
        a1 = tau_step(ti, li, v1, a1);
        a2 = tau_step(ti, li, v2, a2);
        a3 = tau_step(ti, li, v3, a3);
    }
    float acc = (a0 + a1) + (a2 + a3);

    // Wave (64-lane) shuffle reduction, then cross-wave via LDS.
    for (int off = 32; off >= 1; off >>= 1)
        acc += __shfl_down(acc, off, 64);
    if ((tid & 63) == 0) wsum[tid >> 6] = acc;
    __syncthreads();
    if (tid == 0) {
        float t = 0.f;
        for (int w = 0; w < TAU_BLOCK / 64; ++w) t += wsum[w];
        partials[blockIdx.x] = t;
    }
}

__global__ __launch_bounds__(TAU_NBLOCKS) void tau_finalize_kernel(
        const float* __restrict__ partials, float* __restrict__ out) {
    __shared__ float wsum[TAU_NBLOCKS / 64];
    const int tid = threadIdx.x;          // TAU_NBLOCKS threads
    float acc = partials[tid];
    for (int off = 32; off >= 1; off >>= 1)
        acc += __shfl_down(acc, off, 64);
    if ((tid & 63) == 0) wsum[tid >> 6] = acc;
    __syncthreads();
    if (tid == 0) {
        float t = 0.f;
        for (int w = 0; w < TAU_NBLOCKS / 64; ++w) t += wsum[w];
        const float scale = 1.0f / ((float)TAU_N * (float)(TAU_N - 1) * (float)TAU_C);
        out[0] = 1.0f - t * scale;
    }
}

extern "C" void kernel_launch(void* const* d_in, const int* in_sizes, int n_in,
                              void* d_out, int out_size, void* d_ws, size_t ws_size,
                              hipStream_t stream) {
    const float* pred = (const float*)d_in[0];
    const float* y    = (const float*)d_in[1];
    float* out        = (float*)d_out;
    float* partials   = (float*)d_ws;   // TAU_NBLOCKS floats; each written exactly once

    tau_pairs_kernel<<<TAU_NBLOCKS, TAU_BLOCK, 0, stream>>>(pred, y, partials);
    tau_finalize_kernel<<<1, TAU_NBLOCKS, 0, stream>>>(partials, out);
}